// Round 1
// baseline (899.669 us; speedup 1.0000x reference)
//
#include <hip/hip_runtime.h>

#define NCH 64

// ---------------- degree ----------------
__global__ void deg_count(const int* __restrict__ dst, int E, float* __restrict__ deg) {
    int i = blockIdx.x * blockDim.x + threadIdx.x;
    if (i < E) atomicAdd(&deg[dst[i]], 1.0f);
}

__global__ void deg_to_dinv(float* __restrict__ deg, int n) {
    int i = blockIdx.x * blockDim.x + threadIdx.x;
    if (i < n) deg[i] = rsqrtf(deg[i] + 1.0f);  // +1 for self-loop
}

// ---------------- GEMM: Y[n,64] = X[n,64] @ W[64,64] ----------------
__global__ __launch_bounds__(256) void gemm64(const float* __restrict__ X,
                                              const float* __restrict__ W,
                                              float* __restrict__ Y, int n) {
    __shared__ float Ws[64][64];   // 16 KB
    __shared__ float Xs[4][64];    // 1 KB
    int tid = threadIdx.x;
    for (int i = tid; i < 4096; i += 256) Ws[i >> 6][i & 63] = W[i];
    int r = tid >> 6, c = tid & 63;
    int row = blockIdx.x * 4 + r;
    Xs[r][c] = (row < n) ? X[(size_t)row * NCH + c] : 0.0f;
    __syncthreads();
    float acc = 0.0f;
#pragma unroll
    for (int k = 0; k < 64; ++k) acc += Xs[r][k] * Ws[k][c];
    if (row < n) Y[(size_t)row * NCH + c] = acc;
}

// ---------------- scatter-add over edges ----------------
// thread t: edge e = t>>6, channel c = t&63
__global__ void scatter64(const float* __restrict__ XW, const int* __restrict__ src,
                          const int* __restrict__ dst, const float* __restrict__ dinv,
                          float* __restrict__ agg, long long total) {
    long long t = (long long)blockIdx.x * blockDim.x + threadIdx.x;
    if (t >= total) return;
    int e = (int)(t >> 6);
    int c = (int)(t & 63);
    int s = src[e];
    int d = dst[e];
    float norm = dinv[s] * dinv[d];
    atomicAdd(&agg[(size_t)d * NCH + c], XW[(size_t)s * NCH + c] * norm);
}

// ---------------- self-loop + bias + relu (in-place into agg -> h) ----------------
__global__ void post64(float* __restrict__ agg, const float* __restrict__ XW,
                       const float* __restrict__ dinv, const float* __restrict__ b, int n) {
    int t = blockIdx.x * blockDim.x + threadIdx.x;
    if (t >= n * NCH) return;
    int i = t >> 6, c = t & 63;
    float di = dinv[i];
    float v = agg[t] + XW[t] * di * di + b[c];
    agg[t] = v > 0.0f ? v : 0.0f;
}

// ---------------- mean-pool per graph + FC + relu ----------------
__global__ __launch_bounds__(256) void pool_fc(const float* __restrict__ H,
                                               const int* __restrict__ batch, int n,
                                               const float* __restrict__ Wfc,
                                               const float* __restrict__ bfc,
                                               float* __restrict__ out) {
    int g = blockIdx.x;
    // lower_bound(batch, g) and lower_bound(batch, g+1) — batch is sorted
    int lo = 0, hi = n;
    while (lo < hi) { int m = (lo + hi) >> 1; if (batch[m] < g) lo = m + 1; else hi = m; }
    int start = lo;
    hi = n;
    while (lo < hi) { int m = (lo + hi) >> 1; if (batch[m] < g + 1) lo = m + 1; else hi = m; }
    int end = lo;
    int count = end - start;

    int sub = threadIdx.x >> 6, c = threadIdx.x & 63;
    float acc = 0.0f;
    for (int i = start + sub; i < end; i += 4) acc += H[(size_t)i * NCH + c];

    __shared__ float part[4][64];
    __shared__ float pooled[64];
    part[sub][c] = acc;
    __syncthreads();
    if (threadIdx.x < 64) {
        float s = part[0][c] + part[1][c] + part[2][c] + part[3][c];
        pooled[c] = s / (float)(count > 1 ? count : 1);
    }
    __syncthreads();
    if (threadIdx.x < 64) {
        float acc2 = bfc[c];
#pragma unroll
        for (int k = 0; k < 64; ++k) acc2 += pooled[k] * Wfc[k * NCH + c];
        out[(size_t)g * NCH + c] = acc2 > 0.0f ? acc2 : 0.0f;
    }
}

extern "C" void kernel_launch(void* const* d_in, const int* in_sizes, int n_in,
                              void* d_out, int out_size, void* d_ws, size_t ws_size,
                              hipStream_t stream) {
    const float* x    = (const float*)d_in[0];
    const int*   ei   = (const int*)d_in[1];
    const int*   batch= (const int*)d_in[2];
    const float* W1   = (const float*)d_in[3];
    const float* b1   = (const float*)d_in[4];
    const float* W2   = (const float*)d_in[5];
    const float* b2   = (const float*)d_in[6];
    const float* Wfc  = (const float*)d_in[7];
    const float* bfc  = (const float*)d_in[8];
    float* out = (float*)d_out;

    int E = in_sizes[1] / 2;
    int n = in_sizes[0] / NCH;
    const int* src = ei;
    const int* dst = ei + E;

    float* ws   = (float*)d_ws;
    float* dinv = ws;                       // n floats
    float* xw   = ws + (1 << 17);           // n*64 floats
    float* agg  = xw + (size_t)n * NCH;     // n*64 floats (also h, in-place)

    // degrees -> dinv
    hipMemsetAsync(dinv, 0, (size_t)n * sizeof(float), stream);
    deg_count<<<(E + 255) / 256, 256, 0, stream>>>(dst, E, dinv);
    deg_to_dinv<<<(n + 255) / 256, 256, 0, stream>>>(dinv, n);

    long long total = (long long)E * NCH;
    int sblocks = (int)((total + 255) / 256);

    // ---- layer 1 ----
    gemm64<<<(n + 3) / 4, 256, 0, stream>>>(x, W1, xw, n);
    hipMemsetAsync(agg, 0, (size_t)n * NCH * sizeof(float), stream);
    scatter64<<<sblocks, 256, 0, stream>>>(xw, src, dst, dinv, agg, total);
    post64<<<(n * NCH + 255) / 256, 256, 0, stream>>>(agg, xw, dinv, b1, n);

    // ---- layer 2 ----  (h1 lives in agg; gemm reads it, writes xw)
    gemm64<<<(n + 3) / 4, 256, 0, stream>>>(agg, W2, xw, n);
    hipMemsetAsync(agg, 0, (size_t)n * NCH * sizeof(float), stream);
    scatter64<<<sblocks, 256, 0, stream>>>(xw, src, dst, dinv, agg, total);
    post64<<<(n * NCH + 255) / 256, 256, 0, stream>>>(agg, xw, dinv, b2, n);

    // ---- pool + fc ----
    pool_fc<<<128, 256, 0, stream>>>(agg, batch, n, Wfc, bfc, out);
}

// Round 2
// 502.074 us; speedup vs baseline: 1.7919x; 1.7919x over previous
//
#include <hip/hip_runtime.h>

#define NCH 64

// ---------------- degree histogram ----------------
__global__ void hist_dst(const int* __restrict__ dst, int E, int* __restrict__ deg) {
    int i = blockIdx.x * blockDim.x + threadIdx.x;
    if (i < E) atomicAdd(&deg[dst[i]], 1);
}

// ---------------- 3-kernel exclusive scan over deg[n] ----------------
__global__ void scan1_blocksum(const int* __restrict__ deg, int n, int* __restrict__ bsum) {
    __shared__ int s[256];
    int t = threadIdx.x;
    int i = blockIdx.x * 256 + t;
    s[t] = (i < n) ? deg[i] : 0;
    __syncthreads();
    for (int o = 128; o > 0; o >>= 1) {
        if (t < o) s[t] += s[t + o];
        __syncthreads();
    }
    if (t == 0) bsum[blockIdx.x] = s[0];
}

__global__ void scan2_exclusive(int* __restrict__ bsum, int nb) {
    // single block of 512; nb <= 512
    __shared__ int s[512];
    int t = threadIdx.x;
    int v = (t < nb) ? bsum[t] : 0;
    s[t] = v;
    __syncthreads();
    for (int o = 1; o < 512; o <<= 1) {
        int x = (t >= o) ? s[t - o] : 0;
        __syncthreads();
        s[t] += x;
        __syncthreads();
    }
    if (t < nb) bsum[t] = s[t] - v;  // exclusive
}

__global__ void scan3_final(const int* __restrict__ deg, const int* __restrict__ bsum,
                            int n, int E, int* __restrict__ offsets,
                            int* __restrict__ cursor, float* __restrict__ dinv) {
    __shared__ int s[256];
    int t = threadIdx.x;
    int i = blockIdx.x * 256 + t;
    int v = (i < n) ? deg[i] : 0;
    s[t] = v;
    __syncthreads();
    for (int o = 1; o < 256; o <<= 1) {
        int x = (t >= o) ? s[t - o] : 0;
        __syncthreads();
        s[t] += x;
        __syncthreads();
    }
    int excl = s[t] - v + bsum[blockIdx.x];
    if (i < n) {
        offsets[i] = excl;
        cursor[i]  = excl;
        dinv[i]    = rsqrtf((float)v + 1.0f);  // +1 self-loop
    }
    if (i == n - 1) offsets[n] = E;
}

// ---------------- bucket fill: sorted[pos] = (src, norm) ----------------
__global__ void fill_csr(const int* __restrict__ src, const int* __restrict__ dst, int E,
                         const float* __restrict__ dinv, int* __restrict__ cursor,
                         int2* __restrict__ sorted) {
    int e = blockIdx.x * blockDim.x + threadIdx.x;
    if (e >= E) return;
    int s = src[e], d = dst[e];
    int pos = atomicAdd(&cursor[d], 1);
    float norm = dinv[s] * dinv[d];
    sorted[pos] = make_int2(s, __float_as_int(norm));
}

// ---------------- GEMM: Y[n,64] = X[n,64] @ W[64,64] ----------------
__global__ __launch_bounds__(256) void gemm64(const float* __restrict__ X,
                                              const float* __restrict__ W,
                                              float* __restrict__ Y, int n) {
    __shared__ float Ws[64][64];   // 16 KB
    __shared__ float Xs[4][64];    // 1 KB
    int tid = threadIdx.x;
    for (int i = tid; i < 4096; i += 256) Ws[i >> 6][i & 63] = W[i];
    int r = tid >> 6, c = tid & 63;
    int row = blockIdx.x * 4 + r;
    Xs[r][c] = (row < n) ? X[(size_t)row * NCH + c] : 0.0f;
    __syncthreads();
    float acc = 0.0f;
#pragma unroll
    for (int k = 0; k < 64; ++k) acc += Xs[r][k] * Ws[k][c];
    if (row < n) Y[(size_t)row * NCH + c] = acc;
}

// ---------------- CSR gather + self-loop + bias + relu, one wave per node ----------------
__global__ __launch_bounds__(256) void gather_fused(const float* __restrict__ XW,
                                                    const int2* __restrict__ sorted,
                                                    const int* __restrict__ offsets,
                                                    const float* __restrict__ dinv,
                                                    const float* __restrict__ b,
                                                    float* __restrict__ H, int n) {
    int wid  = (int)((blockIdx.x * (size_t)blockDim.x + threadIdx.x) >> 6);  // node
    int lane = threadIdx.x & 63;                                             // channel
    if (wid >= n) return;
    int start = offsets[wid], end = offsets[wid + 1];
    float di = dinv[wid];
    float acc = XW[(size_t)wid * NCH + lane] * (di * di);  // self-loop term
    int e = start;
    for (; e + 4 <= end; e += 4) {
        int2 s0 = sorted[e];
        int2 s1 = sorted[e + 1];
        int2 s2 = sorted[e + 2];
        int2 s3 = sorted[e + 3];
        float v0 = XW[(size_t)s0.x * NCH + lane];
        float v1 = XW[(size_t)s1.x * NCH + lane];
        float v2 = XW[(size_t)s2.x * NCH + lane];
        float v3 = XW[(size_t)s3.x * NCH + lane];
        acc += v0 * __int_as_float(s0.y);
        acc += v1 * __int_as_float(s1.y);
        acc += v2 * __int_as_float(s2.y);
        acc += v3 * __int_as_float(s3.y);
    }
    for (; e < end; ++e) {
        int2 s0 = sorted[e];
        acc += XW[(size_t)s0.x * NCH + lane] * __int_as_float(s0.y);
    }
    float v = acc + b[lane];
    H[(size_t)wid * NCH + lane] = v > 0.0f ? v : 0.0f;
}

// ---------------- mean-pool per graph + FC + relu ----------------
__global__ __launch_bounds__(256) void pool_fc(const float* __restrict__ H,
                                               const int* __restrict__ batch, int n,
                                               const float* __restrict__ Wfc,
                                               const float* __restrict__ bfc,
                                               float* __restrict__ out) {
    int g = blockIdx.x;
    int lo = 0, hi = n;
    while (lo < hi) { int m = (lo + hi) >> 1; if (batch[m] < g) lo = m + 1; else hi = m; }
    int start = lo;
    hi = n;
    while (lo < hi) { int m = (lo + hi) >> 1; if (batch[m] < g + 1) lo = m + 1; else hi = m; }
    int end = lo;
    int count = end - start;

    int sub = threadIdx.x >> 6, c = threadIdx.x & 63;
    float acc = 0.0f;
    for (int i = start + sub; i < end; i += 4) acc += H[(size_t)i * NCH + c];

    __shared__ float part[4][64];
    __shared__ float pooled[64];
    part[sub][c] = acc;
    __syncthreads();
    if (threadIdx.x < 64) {
        float s = part[0][c] + part[1][c] + part[2][c] + part[3][c];
        pooled[c] = s / (float)(count > 1 ? count : 1);
    }
    __syncthreads();
    if (threadIdx.x < 64) {
        float acc2 = bfc[c];
#pragma unroll
        for (int k = 0; k < 64; ++k) acc2 += pooled[k] * Wfc[k * NCH + c];
        out[(size_t)g * NCH + c] = acc2 > 0.0f ? acc2 : 0.0f;
    }
}

static inline size_t align256(size_t x) { return (x + 255) & ~(size_t)255; }

extern "C" void kernel_launch(void* const* d_in, const int* in_sizes, int n_in,
                              void* d_out, int out_size, void* d_ws, size_t ws_size,
                              hipStream_t stream) {
    const float* x     = (const float*)d_in[0];
    const int*   ei    = (const int*)d_in[1];
    const int*   batch = (const int*)d_in[2];
    const float* W1    = (const float*)d_in[3];
    const float* b1    = (const float*)d_in[4];
    const float* W2    = (const float*)d_in[5];
    const float* b2    = (const float*)d_in[6];
    const float* Wfc   = (const float*)d_in[7];
    const float* bfc   = (const float*)d_in[8];
    float* out = (float*)d_out;

    int E = in_sizes[1] / 2;
    int n = in_sizes[0] / NCH;
    const int* src = ei;
    const int* dst = ei + E;

    char* p = (char*)d_ws;
    int*   deg     = (int*)p;   p += align256((size_t)n * 4);
    int*   cursor  = (int*)p;   p += align256((size_t)n * 4);
    int*   offsets = (int*)p;   p += align256((size_t)(n + 1) * 4);
    float* dinv    = (float*)p; p += align256((size_t)n * 4);
    int2*  sorted  = (int2*)p;  p += align256((size_t)E * 8);
    float* xw      = (float*)p; p += align256((size_t)n * NCH * 4);
    float* h       = (float*)p;

    int nb = (n + 255) / 256;

    // ---- CSR build (shared by both layers) ----
    hipMemsetAsync(deg, 0, (size_t)n * sizeof(int), stream);
    hist_dst<<<(E + 255) / 256, 256, 0, stream>>>(dst, E, deg);
    scan1_blocksum<<<nb, 256, 0, stream>>>(deg, n, cursor /*tmp bsum*/);
    // reuse cursor as bsum temporarily? NO — scan3 writes cursor. Use a dedicated tail of ws.
    // (bsum is small: nb ints). Place it after h:
    // -- handled below with bsum pointer --
    // NOTE: the two lines above are replaced by the correct sequence below.
    (void)0;

    // correct sequence with dedicated bsum
    int* bsum = (int*)(p + align256((size_t)n * NCH * 4));  // after h
    scan1_blocksum<<<nb, 256, 0, stream>>>(deg, n, bsum);
    scan2_exclusive<<<1, 512, 0, stream>>>(bsum, nb);
    scan3_final<<<nb, 256, 0, stream>>>(deg, bsum, n, E, offsets, cursor, dinv);
    fill_csr<<<(E + 255) / 256, 256, 0, stream>>>(src, dst, E, dinv, cursor, sorted);

    // ---- layer 1 ----
    gemm64<<<(n + 3) / 4, 256, 0, stream>>>(x, W1, xw, n);
    gather_fused<<<(n * NCH + 255) / 256, 256, 0, stream>>>(xw, sorted, offsets, dinv, b1, h, n);

    // ---- layer 2 ----
    gemm64<<<(n + 3) / 4, 256, 0, stream>>>(h, W2, xw, n);
    gather_fused<<<(n * NCH + 255) / 256, 256, 0, stream>>>(xw, sorted, offsets, dinv, b2, h, n);

    // ---- pool + fc ----
    pool_fc<<<128, 256, 0, stream>>>(h, batch, n, Wfc, bfc, out);
}